// Round 5
// baseline (313.416 us; speedup 1.0000x reference)
//
#include <hip/hip_runtime.h>
#include <stdint.h>
#include <stddef.h>

// ---------------------------------------------------------------------------
// QuantizedLinear: y = x @ (scale*(Wq - zp))^T + bias
// GEMM view: M=8192, N=4096, K=4096.
// R5: 256x256 tile, BK=64, 8 waves (2Mx4N), dbuf LDS (128KiB), m201-style
// 4-phase/K-tile schedule: per phase {6-avg ds_reads + 1 stage unit ->
// s_barrier -> lgkmcnt(0)+sched_barrier -> setprio(1) 16 MFMA setprio(0)
// -> [VMCNT(4) at phases 2,4] -> s_barrier}. Per-phase DS (440-585cy/CU)
// fits under per-phase MFMA (620cy/SIMD); vmcnt cover 2-3 phases (>HBM lat).
// Chunk-XOR swizzle both-sides (rule #21), XCD block swizzle.
// ---------------------------------------------------------------------------

typedef __attribute__((ext_vector_type(4))) float   f32x4;
typedef __attribute__((ext_vector_type(8))) short   short8;   // 8 x bf16
typedef __attribute__((ext_vector_type(4))) int     i32x4;
typedef __attribute__((ext_vector_type(8))) unsigned short ushort8;
typedef __attribute__((ext_vector_type(4))) unsigned short ushort4v;

__device__ __forceinline__ unsigned short f2bf(float f) {
  union { float f; unsigned u; } v; v.f = f;
  unsigned u = v.u;
  u += 0x7fffu + ((u >> 16) & 1u);      // RNE to bf16
  return (unsigned short)(u >> 16);
}

__device__ __forceinline__ void gld_lds16(const void* g, void* l) {
  __builtin_amdgcn_global_load_lds(
      (const __attribute__((address_space(1))) unsigned int*)g,
      (__attribute__((address_space(3))) unsigned int*)l,
      16, 0, 0);
}

__device__ __forceinline__ unsigned ldsAddr(const void* p) {
  return (unsigned)(size_t)(const __attribute__((address_space(3))) void*)p;
}

__device__ __forceinline__ void wgb() {
  asm volatile("" ::: "memory");
  __builtin_amdgcn_s_barrier();
  asm volatile("" ::: "memory");
}

#define DSR(dst, addr, OFF) \
  asm volatile("ds_read_b128 %0, %1 offset:" #OFF : "=v"(dst) : "v"(addr))
#define LGKM0() do { asm volatile("s_waitcnt lgkmcnt(0)" ::: "memory"); \
                     __builtin_amdgcn_sched_barrier(0); } while (0)
#define VMCNT(N) asm volatile("s_waitcnt vmcnt(" #N ")" ::: "memory")

// ---------- prepass: x fp32 -> bf16 ----------
__global__ __launch_bounds__(256) void cvt_x_kernel(
    const f32x4* __restrict__ x, ushort8* __restrict__ o, int n8) {
  int i = blockIdx.x * 256 + threadIdx.x;
  if (i >= n8) return;
  f32x4 a = x[2 * i], b = x[2 * i + 1];
  ushort8 r;
  r[0] = f2bf(a[0]); r[1] = f2bf(a[1]); r[2] = f2bf(a[2]); r[3] = f2bf(a[3]);
  r[4] = f2bf(b[0]); r[5] = f2bf(b[1]); r[6] = f2bf(b[2]); r[7] = f2bf(b[3]);
  o[i] = r;
}

// ---------- prepass: Wq int32 -> bf16 of (q - zp) ----------
__global__ __launch_bounds__(256) void cvt_w_kernel(
    const i32x4* __restrict__ q, ushort8* __restrict__ o,
    const float* __restrict__ zp_p, int n8) {
  int i = blockIdx.x * 256 + threadIdx.x;
  if (i >= n8) return;
  float zp = zp_p[0];
  i32x4 a = q[2 * i], b = q[2 * i + 1];
  ushort8 r;
  r[0] = f2bf((float)a[0] - zp); r[1] = f2bf((float)a[1] - zp);
  r[2] = f2bf((float)a[2] - zp); r[3] = f2bf((float)a[3] - zp);
  r[4] = f2bf((float)b[0] - zp); r[5] = f2bf((float)b[1] - zp);
  r[6] = f2bf((float)b[2] - zp); r[7] = f2bf((float)b[3] - zp);
  o[i] = r;
}

// ---------------------------------------------------------------------------
// Main 256^2 GEMM, 4-phase/K-tile m201-style pipeline.
// LDS region (buf,kh): [256 rows][32 k] bf16 = 16 KiB, staged linearly;
// logical chunk c of row r stored at chunk position c ^ ((r>>1)&3).
// Stage schedule per tile t: ph0->A_kh0(t+1), ph1->B_kh0(t+1),
// ph2->A_kh1(t+1), ph3->B_kh1(t+1). VMCNT(4) at ph1/ph3 end guarantees
// {A,B}_kh1(t) resp. {A,B}_kh0(t+1) resident (staged 2-3 phases earlier).
// ---------------------------------------------------------------------------
__global__ __launch_bounds__(512, 2) void qgemm256_kernel(
    const unsigned short* __restrict__ A,   // [M][K] bf16 (x)
    const unsigned short* __restrict__ B,   // [N][K] bf16 (dequant W)
    const float* __restrict__ bias, const float* __restrict__ scale_p,
    float* __restrict__ C, int M, int N, int K) {
  __shared__ __attribute__((aligned(16))) unsigned short sA[2 * 2 * 8192];
  __shared__ __attribute__((aligned(16))) unsigned short sB[2 * 2 * 8192];

  const int tid  = threadIdx.x;
  const int lane = tid & 63;
  const int w    = tid >> 6;         // 0..7
  const int wr   = w >> 2;           // 0..1  (M strip of 128)
  const int wc   = w & 3;            // 0..3  (N strip of 64)

  // XCD-aware block swizzle (bijective when nwg % 8 == 0)
  const int nwg = gridDim.x;
  const int bid = blockIdx.x;
  const int swz = ((nwg & 7) == 0) ? ((bid & 7) * (nwg >> 3) + (bid >> 3)) : bid;
  const int ntn = N >> 8;
  const int bm0 = (swz / ntn) << 8;
  const int bn0 = (swz % ntn) << 8;

  const int l16 = lane & 15;
  const int l4  = lane >> 4;                       // 0..3 -> k chunk
  const int rchk = (l4 ^ ((l16 >> 1) & 3)) << 4;   // swizzled chunk byte off

  // per-lane LDS read byte bases within a 16 KiB (buf,kh) region
  const unsigned aBase = (unsigned)((wr * 128 + l16) * 64 + rchk);
  const unsigned bBase = (unsigned)((wc * 64 + l16) * 64 + rchk);
  const unsigned sAaddr = ldsAddr(sA);
  const unsigned sBaddr = ldsAddr(sB);

  // staging: thread covers rows (tid>>2) and (tid>>2)+128, one 16B chunk
  const int    st0  = tid, st1 = tid + 512;
  const size_t rK0  = (size_t)(tid >> 2) * K;
  const size_t rK1  = (size_t)((tid >> 2) + 128) * K;
  const int    csrc = ((tid & 3) ^ ((tid >> 3) & 3)) << 3;  // swizzled src k-elems

  const unsigned short* Ab = A + (size_t)bm0 * K;
  const unsigned short* Bb = B + (size_t)bn0 * K;

  f32x4 acc[8][4] = {};
  const int nkt = K >> 6;

#define STAGE_A(NX, H, KOFF) do {                                        \
    unsigned short* _d = sA + ((((NX) << 1) + (H)) << 13);               \
    gld_lds16(Ab + rK0 + (KOFF) + ((H) << 5) + csrc, _d + (st0 << 3));   \
    gld_lds16(Ab + rK1 + (KOFF) + ((H) << 5) + csrc, _d + (st1 << 3));   \
  } while (0)
#define STAGE_B(NX, H, KOFF) do {                                        \
    unsigned short* _d = sB + ((((NX) << 1) + (H)) << 13);               \
    gld_lds16(Bb + rK0 + (KOFF) + ((H) << 5) + csrc, _d + (st0 << 3));   \
    gld_lds16(Bb + rK1 + (KOFF) + ((H) << 5) + csrc, _d + (st1 << 3));   \
  } while (0)

  // ---- prologue: tile0's 4 units; kh0 resident, kh1 (4 loads) in flight ----
  STAGE_A(0, 0, 0); STAGE_B(0, 0, 0);
  STAGE_A(0, 1, 0); STAGE_B(0, 1, 0);
  VMCNT(4);
  wgb();

  for (int kt = 0; kt < nkt; ++kt) {
    const int cur = kt & 1, nx = cur ^ 1;
    const bool pf = (kt + 1 < nkt);
    const int kn = (kt + 1) << 6;

    short8 a[4], b[4], a2[4];

#pragma unroll
    for (int h = 0; h < 2; ++h) {
      const unsigned aR = sAaddr + (unsigned)(((cur << 1) + h) << 14) + aBase;
      const unsigned bR = sBaddr + (unsigned)(((cur << 1) + h) << 14) + bBase;

      // ================= phase 2h (c_even): 8 reads, 1 stage, 16 MFMA ====
      DSR(a[0], aR, 0);    DSR(a[1], aR, 1024); DSR(a[2], aR, 2048); DSR(a[3], aR, 3072);
      DSR(b[0], bR, 0);    DSR(b[1], bR, 1024); DSR(b[2], bR, 2048); DSR(b[3], bR, 3072);
      if (pf) { if (h == 0) STAGE_A(nx, 0, kn); else STAGE_A(nx, 1, kn); }
      wgb();
      LGKM0();
      __builtin_amdgcn_s_setprio(1);
#pragma unroll
      for (int m = 0; m < 4; ++m)
#pragma unroll
        for (int n = 0; n < 4; ++n)
          acc[m][n] = __builtin_amdgcn_mfma_f32_16x16x32_bf16(a[m], b[n], acc[m][n], 0, 0, 0);
      __builtin_amdgcn_s_setprio(0);
      wgb();

      // ================= phase 2h+1 (c_odd): 4 reads, 1 stage, 16 MFMA ===
      DSR(a2[0], aR, 4096); DSR(a2[1], aR, 5120); DSR(a2[2], aR, 6144); DSR(a2[3], aR, 7168);
      if (pf) { if (h == 0) STAGE_B(nx, 0, kn); else STAGE_B(nx, 1, kn); }
      wgb();
      LGKM0();
      __builtin_amdgcn_s_setprio(1);
#pragma unroll
      for (int m = 0; m < 4; ++m)
#pragma unroll
        for (int n = 0; n < 4; ++n)
          acc[4 + m][n] = __builtin_amdgcn_mfma_f32_16x16x32_bf16(a2[m], b[n], acc[4 + m][n], 0, 0, 0);
      __builtin_amdgcn_s_setprio(0);
      // counted vmcnt: h0-end covers {A,B}_kh1(t) (staged t-1 ph2/ph3);
      // h1-end covers {A,B}_kh0(t+1) (staged this tile ph0/ph1).
      if (pf) {
        VMCNT(4); wgb();
      } else if (h == 0) {
        VMCNT(0); wgb();
      }
      // last phase of last tile: no further LDS use -> no sync
    }
  }
#undef STAGE_A
#undef STAGE_B

  // ---- epilogue: y = scale*acc + bias ----
  const float s = scale_p[0];
#pragma unroll
  for (int nf = 0; nf < 4; ++nf) {
    const int col = bn0 + wc * 64 + nf * 16 + l16;
    const float bv = bias[col];
#pragma unroll
    for (int mf = 0; mf < 8; ++mf) {
      const int row0 = bm0 + wr * 128 + mf * 16 + (l4 << 2);
#pragma unroll
      for (int j = 0; j < 4; ++j)
        C[(size_t)(row0 + j) * N + col] = fmaf(s, acc[mf][nf][j], bv);
    }
  }
}

// ---------------------------------------------------------------------------
// Fallback (no workspace): R1's fused 128^2 kernel.
// ---------------------------------------------------------------------------
__global__ __launch_bounds__(256) void qgemm_fused_kernel(
    const float* __restrict__ A, const int* __restrict__ B,
    const float* __restrict__ bias, const float* __restrict__ scale_p,
    const float* __restrict__ zp_p, float* __restrict__ C,
    int M, int N, int K) {
  constexpr int BK = 32;
  __shared__ unsigned short sAf[128 * BK];
  __shared__ unsigned short sBf[128 * BK];
  const int tid = threadIdx.x, lane = tid & 63, w = tid >> 6;
  const int wr = w >> 1, wc = w & 1;
  const int bm0 = blockIdx.y * 128, bn0 = blockIdx.x * 128;
  const int l16 = lane & 15, lk = (lane >> 4) << 3;
  const float zp = zp_p[0];
  f32x4 acc[4][4] = {};
  for (int k0 = 0; k0 < K; k0 += BK) {
#pragma unroll
    for (int c = 0; c < 4; ++c) {
      int ch = c * 256 + tid;
      int row = ch >> 3, c4 = (ch & 7) << 2;
      f32x4 av = *(const f32x4*)(A + (size_t)(bm0 + row) * K + k0 + c4);
      i32x4 bv = *(const i32x4*)(B + (size_t)(bn0 + row) * K + k0 + c4);
      ushort4v ra, rb;
      ra[0] = f2bf(av[0]); ra[1] = f2bf(av[1]); ra[2] = f2bf(av[2]); ra[3] = f2bf(av[3]);
      rb[0] = f2bf((float)bv[0] - zp); rb[1] = f2bf((float)bv[1] - zp);
      rb[2] = f2bf((float)bv[2] - zp); rb[3] = f2bf((float)bv[3] - zp);
      *(ushort4v*)&sAf[row * BK + c4] = ra;
      *(ushort4v*)&sBf[row * BK + c4] = rb;
    }
    __syncthreads();
    short8 a[4], b[4];
#pragma unroll
    for (int m = 0; m < 4; ++m) a[m] = *(const short8*)&sAf[(wr * 64 + m * 16 + l16) * BK + lk];
#pragma unroll
    for (int n = 0; n < 4; ++n) b[n] = *(const short8*)&sBf[(wc * 64 + n * 16 + l16) * BK + lk];
#pragma unroll
    for (int m = 0; m < 4; ++m)
#pragma unroll
      for (int n = 0; n < 4; ++n)
        acc[m][n] = __builtin_amdgcn_mfma_f32_16x16x32_bf16(a[m], b[n], acc[m][n], 0, 0, 0);
    __syncthreads();
  }
  const float s = scale_p[0];
#pragma unroll
  for (int n = 0; n < 4; ++n) {
    const int col = bn0 + wc * 64 + n * 16 + l16;
    const float bv = bias[col];
#pragma unroll
    for (int m = 0; m < 4; ++m) {
      const int row0 = bm0 + wr * 64 + m * 16 + ((lane >> 4) << 2);
#pragma unroll
      for (int j = 0; j < 4; ++j)
        C[(size_t)(row0 + j) * N + col] = fmaf(s, acc[m][n][j], bv);
    }
  }
}

extern "C" void kernel_launch(void* const* d_in, const int* in_sizes, int n_in,
                              void* d_out, int out_size, void* d_ws, size_t ws_size,
                              hipStream_t stream) {
  const float* x     = (const float*)d_in[0];
  const int*   wq    = (const int*)d_in[1];
  const float* bias  = (const float*)d_in[2];
  const float* scale = (const float*)d_in[3];
  const float* zp    = (const float*)d_in[4];
  float*       out   = (float*)d_out;

  const int K = 4096;
  const int N = in_sizes[1] / K;      // 4096
  const int M = in_sizes[0] / K;      // 8192

  const size_t xb_elems = (size_t)M * K;
  const size_t wb_elems = (size_t)N * K;
  const size_t need = (xb_elems + wb_elems) * sizeof(unsigned short);

  if (ws_size >= need && (M % 256 == 0) && (N % 256 == 0) && (K % 64 == 0)) {
    unsigned short* xb = (unsigned short*)d_ws;
    unsigned short* wb = xb + xb_elems;
    int nx8 = (int)(xb_elems / 8), nw8 = (int)(wb_elems / 8);
    cvt_x_kernel<<<(nx8 + 255) / 256, 256, 0, stream>>>((const f32x4*)x, (ushort8*)xb, nx8);
    cvt_w_kernel<<<(nw8 + 255) / 256, 256, 0, stream>>>((const i32x4*)wq, (ushort8*)wb, zp, nw8);
    dim3 grid((M >> 8) * (N >> 8));
    qgemm256_kernel<<<grid, 512, 0, stream>>>(xb, wb, bias, scale, out, M, N, K);
  } else {
    dim3 grid(N / 128, M / 128);
    qgemm_fused_kernel<<<grid, 256, 0, stream>>>(x, wq, bias, scale, zp, out, M, N, K);
  }
}